// Round 10
// baseline (380.984 us; speedup 1.0000x reference)
//
#include <hip/hip_runtime.h>
#include <math.h>

#define UT 1024
#define XS 52      // x-buffer row stride
#define ASTR 66    // A-buffer row stride (even -> b64 rows)

// ---- shared-memory carve (float indices), total 16160 floats = 64640 B ----
#define SA    0        // 4224  A ping / nnconv1 xl region partner
#define SB    4224     // 4224  A pong / nnconv1 xl
#define SX0   8448     // 3328  x ping / build scratch / agg1
#define SX1   11776    // 3328  x pong / rwl1 + edge arrays
#define SSCR  15104    // 64
#define SDIS  15168    // 64
#define SDIS0 15232    // 64
#define SSVL  15296    // 64
#define SPERM 15360    // 192 ints
#define SCSRO 15552    // 65 ints
#define SCSRC 15617    // 512 ints
#define SMSZ  16160

__device__ __forceinline__ float wred16(float v) {
    v += __shfl_xor(v, 8); v += __shfl_xor(v, 4);
    v += __shfl_xor(v, 2); v += __shfl_xor(v, 1);
    return v;
}

// ---------------------------------------------------------------------------
// Dense GCN (proven): 2-row x 4-col tiles, b64 A/x reads.
// ---------------------------------------------------------------------------
__device__ __forceinline__ void gcn_u(int n, int cin, int cout,
    float* __restrict__ x, float* __restrict__ tmp,
    const float* __restrict__ A, float* __restrict__ Wl,
    float* __restrict__ dis,
    const float* __restrict__ Wg, const float* __restrict__ bg, bool relu)
{
    const int tid = threadIdx.x;
    const int nso = (cout + 3) >> 2;
    for (int idx = tid; idx < 51 * 52; idx += UT) {
        int r = idx / 52, c = idx - r * 52;
        float v = 0.f;
        if (r < cin && c < cout) v = Wg[r * cout + c];
        else if (r == 50 && c < cout) v = bg[c];
        Wl[idx] = v;
    }
    {
        int r = tid >> 4, l = tid & 15;
        float s = 0.f;
        if (r < n) for (int j = l; j < n; j += 16) s += A[r * ASTR + j];
        s = wred16(s);
        if (l == 0 && r < n) dis[r] = 1.0f / sqrtf(2.0f + s);
    }
    __syncthreads();
    const int nr2 = n >> 1;
    const int items = nr2 * nso;
    for (int it = tid; it < items; it += UT) {
        int i0 = (it / nso) * 2, o0 = (it - (it / nso) * nso) * 4;
        float a0=0,a1=0,a2=0,a3=0, b0=0,b1=0,b2=0,b3=0;
        float c0=0,c1=0,c2=0,c3=0, d0=0,d1=0,d2=0,d3=0;
        for (int k = 0; k < cin; k += 2) {
            float4 w0 = *(const float4*)&Wl[k * 52 + o0];
            float4 w1 = *(const float4*)&Wl[(k + 1) * 52 + o0];
            float2 xa = *(const float2*)&x[i0 * XS + k];
            float2 xb = *(const float2*)&x[(i0 + 1) * XS + k];
            a0 = fmaf(xa.x, w0.x, a0); a1 = fmaf(xa.x, w0.y, a1);
            a2 = fmaf(xa.x, w0.z, a2); a3 = fmaf(xa.x, w0.w, a3);
            b0 = fmaf(xa.y, w1.x, b0); b1 = fmaf(xa.y, w1.y, b1);
            b2 = fmaf(xa.y, w1.z, b2); b3 = fmaf(xa.y, w1.w, b3);
            c0 = fmaf(xb.x, w0.x, c0); c1 = fmaf(xb.x, w0.y, c1);
            c2 = fmaf(xb.x, w0.z, c2); c3 = fmaf(xb.x, w0.w, c3);
            d0 = fmaf(xb.y, w1.x, d0); d1 = fmaf(xb.y, w1.y, d1);
            d2 = fmaf(xb.y, w1.z, d2); d3 = fmaf(xb.y, w1.w, d3);
        }
        float e0 = dis[i0], e1 = dis[i0 + 1];
        float4 t0, t1;
        t0.x = (a0 + b0) * e0; t0.y = (a1 + b1) * e0;
        t0.z = (a2 + b2) * e0; t0.w = (a3 + b3) * e0;
        t1.x = (c0 + d0) * e1; t1.y = (c1 + d1) * e1;
        t1.z = (c2 + d2) * e1; t1.w = (c3 + d3) * e1;
        *(float4*)&tmp[i0 * XS + o0] = t0;
        *(float4*)&tmp[(i0 + 1) * XS + o0] = t1;
    }
    __syncthreads();
    for (int it = tid; it < items; it += UT) {
        int i0 = (it / nso) * 2, o0 = (it - (it / nso) * nso) * 4;
        float a0=0,a1=0,a2=0,a3=0, b0=0,b1=0,b2=0,b3=0;
        float c0=0,c1=0,c2=0,c3=0, d0=0,d1=0,d2=0,d3=0;
        for (int j = 0; j < n; j += 2) {
            float4 t0 = *(const float4*)&tmp[j * XS + o0];
            float4 t1 = *(const float4*)&tmp[(j + 1) * XS + o0];
            float2 Aa2 = *(const float2*)&A[i0 * ASTR + j];
            float2 Ab2 = *(const float2*)&A[(i0 + 1) * ASTR + j];
            a0 = fmaf(Aa2.x, t0.x, a0); a1 = fmaf(Aa2.x, t0.y, a1);
            a2 = fmaf(Aa2.x, t0.z, a2); a3 = fmaf(Aa2.x, t0.w, a3);
            b0 = fmaf(Aa2.y, t1.x, b0); b1 = fmaf(Aa2.y, t1.y, b1);
            b2 = fmaf(Aa2.y, t1.z, b2); b3 = fmaf(Aa2.y, t1.w, b3);
            c0 = fmaf(Ab2.x, t0.x, c0); c1 = fmaf(Ab2.x, t0.y, c1);
            c2 = fmaf(Ab2.x, t0.z, c2); c3 = fmaf(Ab2.x, t0.w, c3);
            d0 = fmaf(Ab2.y, t1.x, d0); d1 = fmaf(Ab2.y, t1.y, d1);
            d2 = fmaf(Ab2.y, t1.z, d2); d3 = fmaf(Ab2.y, t1.w, d3);
        }
        float4 bias = *(const float4*)&Wl[50 * 52 + o0];
        float4 s0 = *(const float4*)&tmp[i0 * XS + o0];
        float4 s1 = *(const float4*)&tmp[(i0 + 1) * XS + o0];
        float e0 = dis[i0], e1 = dis[i0 + 1];
        float4 r0, r1;
        r0.x = fmaf(e0, (a0 + b0) + 2.f * s0.x, bias.x);
        r0.y = fmaf(e0, (a1 + b1) + 2.f * s0.y, bias.y);
        r0.z = fmaf(e0, (a2 + b2) + 2.f * s0.z, bias.z);
        r0.w = fmaf(e0, (a3 + b3) + 2.f * s0.w, bias.w);
        r1.x = fmaf(e1, (c0 + d0) + 2.f * s1.x, bias.x);
        r1.y = fmaf(e1, (c1 + d1) + 2.f * s1.y, bias.y);
        r1.z = fmaf(e1, (c2 + d2) + 2.f * s1.z, bias.z);
        r1.w = fmaf(e1, (c3 + d3) + 2.f * s1.w, bias.w);
        if (relu) {
            r0.x = fmaxf(r0.x, 0.f); r0.y = fmaxf(r0.y, 0.f);
            r0.z = fmaxf(r0.z, 0.f); r0.w = fmaxf(r0.w, 0.f);
            r1.x = fmaxf(r1.x, 0.f); r1.y = fmaxf(r1.y, 0.f);
            r1.z = fmaxf(r1.z, 0.f); r1.w = fmaxf(r1.w, 0.f);
        }
        *(float4*)&x[i0 * XS + o0] = r0;
        *(float4*)&x[(i0 + 1) * XS + o0] = r1;
    }
    __syncthreads();
}

// ---------------------------------------------------------------------------
// Sparse GCN (proven): original binary adjacency via dedup CSR.
// ---------------------------------------------------------------------------
__device__ __forceinline__ void gcn_sparse(int cin, int cout,
    float* __restrict__ x, float* __restrict__ tmp,
    const int* __restrict__ csrOff, const int* __restrict__ csrCol,
    float* __restrict__ dis0, float* __restrict__ Wl,
    const float* __restrict__ Wg, const float* __restrict__ bg, bool relu)
{
    const int tid = threadIdx.x;
    const int nso = (cout + 3) >> 2;
    for (int idx = tid; idx < 51 * 52; idx += UT) {
        int r = idx / 52, c = idx - r * 52;
        float v = 0.f;
        if (r < cin && c < cout) v = Wg[r * cout + c];
        else if (r == 50 && c < cout) v = bg[c];
        Wl[idx] = v;
    }
    if (tid < 64)
        dis0[tid] = 1.0f / sqrtf(2.0f + (float)(csrOff[tid + 1] - csrOff[tid]));
    __syncthreads();
    const int items1 = 32 * nso;
    if (tid < items1) {
        int i0 = (tid / nso) * 2, o0 = (tid - (tid / nso) * nso) * 4;
        float a0=0,a1=0,a2=0,a3=0, b0=0,b1=0,b2=0,b3=0;
        float c0=0,c1=0,c2=0,c3=0, d0=0,d1=0,d2=0,d3=0;
        for (int k = 0; k < cin; k += 2) {
            float4 w0 = *(const float4*)&Wl[k * 52 + o0];
            float4 w1 = *(const float4*)&Wl[(k + 1) * 52 + o0];
            float2 xa = *(const float2*)&x[i0 * XS + k];
            float2 xb = *(const float2*)&x[(i0 + 1) * XS + k];
            a0 = fmaf(xa.x, w0.x, a0); a1 = fmaf(xa.x, w0.y, a1);
            a2 = fmaf(xa.x, w0.z, a2); a3 = fmaf(xa.x, w0.w, a3);
            b0 = fmaf(xa.y, w1.x, b0); b1 = fmaf(xa.y, w1.y, b1);
            b2 = fmaf(xa.y, w1.z, b2); b3 = fmaf(xa.y, w1.w, b3);
            c0 = fmaf(xb.x, w0.x, c0); c1 = fmaf(xb.x, w0.y, c1);
            c2 = fmaf(xb.x, w0.z, c2); c3 = fmaf(xb.x, w0.w, c3);
            d0 = fmaf(xb.y, w1.x, d0); d1 = fmaf(xb.y, w1.y, d1);
            d2 = fmaf(xb.y, w1.z, d2); d3 = fmaf(xb.y, w1.w, d3);
        }
        float e0 = dis0[i0], e1 = dis0[i0 + 1];
        float4 t0, t1;
        t0.x = (a0 + b0) * e0; t0.y = (a1 + b1) * e0;
        t0.z = (a2 + b2) * e0; t0.w = (a3 + b3) * e0;
        t1.x = (c0 + d0) * e1; t1.y = (c1 + d1) * e1;
        t1.z = (c2 + d2) * e1; t1.w = (c3 + d3) * e1;
        *(float4*)&tmp[i0 * XS + o0] = t0;
        *(float4*)&tmp[(i0 + 1) * XS + o0] = t1;
    }
    __syncthreads();
    const int items = 64 * nso;
    if (tid < items) {
        int i = tid / nso, o0 = (tid - i * nso) * 4;
        int base = csrOff[i], end = csrOff[i + 1];
        float a0 = 0.f, a1 = 0.f, a2 = 0.f, a3 = 0.f;
        for (int p = base; p < end; p++) {
            int j = csrCol[p];
            float4 t = *(const float4*)&tmp[j * XS + o0];
            a0 += t.x; a1 += t.y; a2 += t.z; a3 += t.w;
        }
        float4 bias = *(const float4*)&Wl[50 * 52 + o0];
        float4 s0 = *(const float4*)&tmp[i * XS + o0];
        float d = dis0[i];
        float4 r;
        r.x = fmaf(d, a0 + 2.f * s0.x, bias.x);
        r.y = fmaf(d, a1 + 2.f * s0.y, bias.y);
        r.z = fmaf(d, a2 + 2.f * s0.z, bias.z);
        r.w = fmaf(d, a3 + 2.f * s0.w, bias.w);
        if (relu) {
            r.x = fmaxf(r.x, 0.f); r.y = fmaxf(r.y, 0.f);
            r.z = fmaxf(r.z, 0.f); r.w = fmaxf(r.w, 0.f);
        }
        *(float4*)&x[i * XS + o0] = r;
    }
    __syncthreads();
}

// ---------------------------------------------------------------------------
__device__ __forceinline__ void down_scores(int n, const float* __restrict__ wg,
                                            const float* __restrict__ px,
                                            float* __restrict__ scr)
{
    const int tid = threadIdx.x;
    int r = tid >> 4, l = tid & 15;
    float s = 0.f, wn = 0.f;
    for (int q = l; q < 50; q += 16) {
        float wv = wg[q];
        wn = fmaf(wv, wv, wn);
        s  = fmaf(px[r * XS + q], wv, s);
    }
    s = wred16(s); wn = wred16(wn);
    if (l == 0 && r < n) scr[r] = tanhf(s / sqrtf(wn));
}

__device__ __forceinline__ void down_rest(int n, int kk,
    float* __restrict__ px, float* __restrict__ pt_,
    float* __restrict__ pA, float* __restrict__ pF,
    float* __restrict__ scr, float* __restrict__ dis, float* __restrict__ svals,
    int* __restrict__ perm, const float* __restrict__ dw,
    const float* __restrict__ db)
{
    const int tid = threadIdx.x;
    __syncthreads();
    if (tid < 64) {   // bitonic top-k (desc score, asc index)
        float v = (tid < n) ? scr[tid] : -2.0f;
        int id = tid;
        for (int sz = 2; sz <= 64; sz <<= 1)
            for (int st = sz >> 1; st > 0; st >>= 1) {
                float ov = __shfl_xor(v, st);
                int oi = __shfl_xor(id, st);
                bool up = ((tid & sz) == 0);
                bool lower = ((tid & st) == 0);
                bool less = (v > ov) || (v == ov && id < oi);
                bool keep = (up == lower) ? less : !less;
                if (!keep) { v = ov; id = oi; }
            }
        if (tid < kk) { perm[tid] = id; svals[tid] = v; }
    }
    __syncthreads();
    for (int idx = tid; idx < n * 13; idx += UT) {
        int m = idx / 13, u0 = (idx - (idx / 13) * 13) * 4;
        float4 gv;
        gv.x = (u0 + 0 < kk) ? pA[m * ASTR + perm[u0 + 0]] : 0.f;
        gv.y = (u0 + 1 < kk) ? pA[m * ASTR + perm[u0 + 1]] : 0.f;
        gv.z = (u0 + 2 < kk) ? pA[m * ASTR + perm[u0 + 2]] : 0.f;
        gv.w = (u0 + 3 < kk) ? pA[m * ASTR + perm[u0 + 3]] : 0.f;
        *(float4*)&pt_[m * XS + u0] = gv;
    }
    float gx0=0, gx1=0, gx2=0, gx3=0; int gdst = -1;
    if (tid < kk * 13) {
        int t = tid / 13, q0 = (tid - t * 13) * 4;
        float sv = svals[t]; int p = perm[t];
        gx0 = px[p * XS + q0 + 0] * sv; gx1 = px[p * XS + q0 + 1] * sv;
        gx2 = px[p * XS + q0 + 2] * sv; gx3 = px[p * XS + q0 + 3] * sv;
        gdst = t * XS + q0;
    }
    __syncthreads();
    if (gdst >= 0) {
        px[gdst] = gx0; px[gdst + 1] = gx1; px[gdst + 2] = gx2; px[gdst + 3] = gx3;
    }
    int nst = (kk + 3) >> 2, kt2 = kk >> 1;
    for (int it = tid; it < kt2 * nst; it += UT) {
        int t0 = (it / nst) * 2, u0 = (it - (it / nst) * nst) * 4;
        int p0 = perm[t0], p1 = perm[t0 + 1];
        float a0=0,a1=0,a2=0,a3=0, b0=0,b1=0,b2=0,b3=0;
        float c0=0,c1=0,c2=0,c3=0, d0=0,d1=0,d2=0,d3=0;
        for (int m = 0; m < n; m += 2) {
            float4 g0 = *(const float4*)&pt_[m * XS + u0];
            float4 g1 = *(const float4*)&pt_[(m + 1) * XS + u0];
            float2 q0v = *(const float2*)&pA[p0 * ASTR + m];
            float2 q1v = *(const float2*)&pA[p1 * ASTR + m];
            a0 = fmaf(q0v.x, g0.x, a0); a1 = fmaf(q0v.x, g0.y, a1);
            a2 = fmaf(q0v.x, g0.z, a2); a3 = fmaf(q0v.x, g0.w, a3);
            b0 = fmaf(q0v.y, g1.x, b0); b1 = fmaf(q0v.y, g1.y, b1);
            b2 = fmaf(q0v.y, g1.z, b2); b3 = fmaf(q0v.y, g1.w, b3);
            c0 = fmaf(q1v.x, g0.x, c0); c1 = fmaf(q1v.x, g0.y, c1);
            c2 = fmaf(q1v.x, g0.z, c2); c3 = fmaf(q1v.x, g0.w, c3);
            d0 = fmaf(q1v.y, g1.x, d0); d1 = fmaf(q1v.y, g1.y, d1);
            d2 = fmaf(q1v.y, g1.z, d2); d3 = fmaf(q1v.y, g1.w, d3);
        }
        float4 gg0 = *(const float4*)&pt_[p0 * XS + u0];
        float4 gg1 = *(const float4*)&pt_[p1 * XS + u0];
        float v;
        v = (a0 + b0) + 2.f * gg0.x; pF[t0 * ASTR + u0 + 0] = (u0 + 0 == t0) ? 0.f : v;
        v = (a1 + b1) + 2.f * gg0.y; pF[t0 * ASTR + u0 + 1] = (u0 + 1 == t0) ? 0.f : v;
        v = (a2 + b2) + 2.f * gg0.z; pF[t0 * ASTR + u0 + 2] = (u0 + 2 == t0) ? 0.f : v;
        v = (a3 + b3) + 2.f * gg0.w; pF[t0 * ASTR + u0 + 3] = (u0 + 3 == t0) ? 0.f : v;
        v = (c0 + d0) + 2.f * gg1.x; pF[(t0+1) * ASTR + u0 + 0] = (u0 + 0 == t0+1) ? 0.f : v;
        v = (c1 + d1) + 2.f * gg1.y; pF[(t0+1) * ASTR + u0 + 1] = (u0 + 1 == t0+1) ? 0.f : v;
        v = (c2 + d2) + 2.f * gg1.z; pF[(t0+1) * ASTR + u0 + 2] = (u0 + 2 == t0+1) ? 0.f : v;
        v = (c3 + d3) + 2.f * gg1.w; pF[(t0+1) * ASTR + u0 + 3] = (u0 + 3 == t0+1) ? 0.f : v;
    }
    __syncthreads();
    gcn_u(kk, 50, 50, px, pt_, pF, pA, dis, dw, db, true);
}

// ---------------------------------------------------------------------------
// Full UNet body on the carved smem (round-8 structure, proven-correct).
// ---------------------------------------------------------------------------
__device__ void unet_body(float* __restrict__ smem,
    const float* __restrict__ xin, const float* __restrict__ wsAg,
    const int* __restrict__ wsCsrO, const int* __restrict__ wsCsrC,
    const float* __restrict__ dw0, const float* __restrict__ db0,
    const float* __restrict__ dws, const float* __restrict__ dbs,
    const float* __restrict__ pws,
    const float* __restrict__ uws, const float* __restrict__ ubs,
    const float* __restrict__ uwl, const float* __restrict__ ubl,
    float* __restrict__ xs_g, float* __restrict__ as_g,
    float* __restrict__ outp, int g, int mean_mode)
{
    const int tid = threadIdx.x;
    float* Aa  = smem + SA;  float* Ab  = smem + SB;
    float* x0c = smem + SX0; float* x1c = smem + SX1;
    float* scr = smem + SSCR; float* dis = smem + SDIS;
    float* dis0 = smem + SDIS0; float* svals = smem + SSVL;
    int* permL = (int*)(smem + SPERM);
    int* csrOffL = (int*)(smem + SCSRO);
    int* csrColL = (int*)(smem + SCSRC);

    float *pA = Aa, *pF = Ab, *px = x0c, *pt_ = x1c;
    const int nsz[4] = {64, 52, 42, 34};

    if (xin) {
        for (int idx = tid; idx < 512; idx += UT) {
            int i = idx >> 3, o0 = (idx & 7) * 4;
            *(float4*)&px[i * XS + o0] = *(const float4*)&xin[i * 32 + o0];
        }
        for (int idx = tid; idx < 4224; idx += UT) pA[idx] = wsAg[idx];
        if (tid < 65) csrOffL[tid] = wsCsrO[tid];
        if (tid >= 128 && tid < 640) csrColL[tid - 128] = wsCsrC[tid - 128];
        __syncthreads();
    }

    gcn_sparse(32, 50, px, pt_, csrOffL, csrColL, dis0, pF, dw0, db0, true);

    for (int lvl = 0; lvl < 3; lvl++) {
        int n = nsz[lvl], kk = nsz[lvl + 1];
        down_scores(n, pws + lvl * 50, px, scr);
        {
            float* xd = xs_g + lvl * 3328;
            for (int idx = tid; idx < 3328; idx += UT) xd[idx] = px[idx];
            if (lvl == 1) for (int idx = tid; idx < 3432; idx += UT) as_g[idx] = pA[idx];
            if (lvl == 2) for (int idx = tid; idx < 2772; idx += UT) as_g[3432 + idx] = pA[idx];
        }
        down_rest(n, kk, px, pt_, pA, pF, scr, dis, svals, permL + lvl * 64,
                  dws + lvl * 2500, dbs + lvl * 50);
        { float* t = pA; pA = pF; pF = t; }
    }

    for (int i2 = 0; i2 < 3; i2++) {
        int j = 2 - i2;
        int kc = nsz[j + 1];
        {
            const float* resg = xs_g + j * 3328;
            for (int idx = tid; idx < 3328; idx += UT) pt_[idx] = resg[idx];
            if (j == 1) {
                for (int idx = tid; idx < 3432; idx += UT) pF[idx] = as_g[idx];
            } else if (j == 2) {
                for (int idx = tid; idx < 2772; idx += UT) pF[idx] = as_g[3432 + idx];
            }
        }
        __syncthreads();
        const int* perm = permL + j * 64;
        for (int it = tid; it < kc * 13; it += UT) {
            int t = it / 13, q0 = (it - t * 13) * 4;
            int p = perm[t];
            pt_[p*XS+q0+0] += px[t*XS+q0+0]; pt_[p*XS+q0+1] += px[t*XS+q0+1];
            pt_[p*XS+q0+2] += px[t*XS+q0+2]; pt_[p*XS+q0+3] += px[t*XS+q0+3];
        }
        __syncthreads();
        if (i2 < 2)
            gcn_u(nsz[j], 50, 50, pt_, px, pF, pA, dis, uws + i2 * 2500, ubs + i2 * 50, true);
        else
            gcn_sparse(50, 32, pt_, px, csrOffL, csrColL, dis0, pF, uwl, ubl, false);
        { float* t2 = px; px = pt_; pt_ = t2; }
        { float* t2 = pA; pA = pF; pF = t2; }
    }
    // final x now in px == smem+SX1

    if (mean_mode == 1) {
        int r = tid >> 4, l = tid & 15;
        if (r < 32) {
            float s = 0.f;
            for (int i = l; i < 64; i += 16) s += fmaxf(px[i * XS + r], 0.f);
            s = wred16(s);
            if (l == 0) outp[(size_t)g * 32 + r] = s * (1.0f / 64.0f);
        }
        __syncthreads();
    }
}

// ---------------------------------------------------------------------------
// NNConv core, dst-grouped, atomic-free. Buffers outputs in registers across
// one barrier so `out` may alias `agg`'s region (LDS) safely.
// ---------------------------------------------------------------------------
template<int FIN>
__device__ __forceinline__ void nnconv_core(
    const float* __restrict__ xl, const float* __restrict__ rwl,
    float* __restrict__ agg,
    const int* __restrict__ dOff, const int* __restrict__ sSrc,
    const float* __restrict__ sEa,
    const float* __restrict__ mw, const float* __restrict__ mb,
    const float* __restrict__ bias, float* __restrict__ out, int ostride)
{
    constexpr int CH = FIN / 2;
    const int tid = threadIdx.x;
    const int o = tid & 31, ic = (tid >> 5) & 1, wv = tid >> 6;
    float mwr[CH], mbr[CH];
    #pragma unroll
    for (int z = 0; z < CH; z++) {
        mwr[z] = mw[(ic * CH + z) * 32 + o];
        mbr[z] = mb[(ic * CH + z) * 32 + o];
    }
    for (int dd = 0; dd < 4; dd++) {
        int d = wv * 4 + dd;                  // wave-uniform
        int b = dOff[d], e = dOff[d + 1];
        float ac0 = 0.f, ac1 = 0.f, ac2 = 0.f, ac3 = 0.f;
        for (int p = b; p < e; p++) {
            int s = sSrc[p];
            float av = sEa[p];
            #pragma unroll
            for (int z = 0; z < CH; z += 4) {
                float4 xv = *(const float4*)&xl[s * FIN + ic * CH + z];
                ac0 = fmaf(xv.x, fmaxf(fmaf(av, mwr[z + 0], mbr[z + 0]), 0.f), ac0);
                ac1 = fmaf(xv.y, fmaxf(fmaf(av, mwr[z + 1], mbr[z + 1]), 0.f), ac1);
                ac2 = fmaf(xv.z, fmaxf(fmaf(av, mwr[z + 2], mbr[z + 2]), 0.f), ac2);
                ac3 = fmaf(xv.w, fmaxf(fmaf(av, mwr[z + 3], mbr[z + 3]), 0.f), ac3);
            }
        }
        float acc = (ac0 + ac1) + (ac2 + ac3);
        acc += __shfl_down(acc, 32);
        if (ic == 0) agg[d * 32 + o] = acc;
    }
    __syncthreads();
    {   // epilogue: regs -> barrier -> store (out may alias agg region)
        int nn = tid >> 4, o0 = (tid & 15) * 2;
        float a0 = 0.f, a1 = 0.f, b0 = 0.f, b1 = 0.f;
        for (int i = 0; i < FIN; i += 2) {
            float xv0 = xl[nn * FIN + i], xv1 = xl[nn * FIN + i + 1];
            float2 w0 = *(const float2*)&rwl[i * 32 + o0];
            float2 w1 = *(const float2*)&rwl[(i + 1) * 32 + o0];
            a0 = fmaf(xv0, w0.x, a0); a1 = fmaf(xv0, w0.y, a1);
            b0 = fmaf(xv1, w1.x, b0); b1 = fmaf(xv1, w1.y, b1);
        }
        float cn  = (float)(dOff[nn + 1] - dOff[nn]);
        float inv = 1.0f / fmaxf(cn, 1.f);
        float2 sv = *(const float2*)&agg[nn * 32 + o0];
        float r0 = fmaxf(fmaf(sv.x, inv, (a0 + b0) + bias[o0]),     0.f);
        float r1 = fmaxf(fmaf(sv.y, inv, (a1 + b1) + bias[o0 + 1]), 0.f);
        __syncthreads();
        out[nn * ostride + o0]     = r0;
        out[nn * ostride + o0 + 1] = r1;
    }
    __syncthreads();
}

// ---------------------------------------------------------------------------
// Fused kernel 1: build + nnconv1 -> unet1 (in LDS) -> nnconv2 -> xc2.
// __launch_bounds__(1024,4): VGPR cap 128 so nnconv weight arrays stay in
// registers (round-8's 64-cap spilled ~95 MB/dispatch to scratch).
// ---------------------------------------------------------------------------
__global__ __launch_bounds__(UT, 4)
void fused1_kernel(const float* __restrict__ x1, const float* __restrict__ x2,
                   const int* __restrict__ ei1, const int* __restrict__ ei2,
                   const float* __restrict__ ea1, const float* __restrict__ ea2,
                   const float* __restrict__ m1w, const float* __restrict__ m1b,
                   const float* __restrict__ r1w, const float* __restrict__ c1b,
                   const float* __restrict__ m2w, const float* __restrict__ m2b,
                   const float* __restrict__ r2w, const float* __restrict__ c2b,
                   const float* __restrict__ u0, const float* __restrict__ u1,
                   const float* __restrict__ u2, const float* __restrict__ u3,
                   const float* __restrict__ u4, const float* __restrict__ u5,
                   const float* __restrict__ u6, const float* __restrict__ u7,
                   const float* __restrict__ u8,
                   float* __restrict__ wsA, int* __restrict__ wsEdg,
                   int* __restrict__ wsCsrO, int* __restrict__ wsCsrC,
                   float* __restrict__ ws_xs, float* __restrict__ ws_As,
                   float* __restrict__ xc2)
{
    const int g = blockIdx.x, tid = threadIdx.x;
    __shared__ __align__(16) float smem[SMSZ];

    // phase-1 aliases
    float* Al   = smem + SA;                   // 4224, becomes unet pA
    float* xl   = smem + SB;                   // 4096
    int*   srcl = (int*)(smem + SX0);          // 512
    int*   dstl = (int*)(smem + SX0 + 512);    // 512
    float* eal  = smem + SX0 + 1024;           // 512
    int*   chunkCnt = (int*)(smem + SX0 + 1536); // 1024
    int*   sTot = (int*)(smem + SX0 + 2560);   // 64
    int*   rowc = (int*)(smem + SX0 + 2624);   // 64
    float* rwl  = smem + SX1;                  // 2048
    int*   dOff = (int*)(smem + SX1 + 2048);   // 65
    int*   sSrc = (int*)(smem + SX1 + 2113);   // 512
    float* sEa  = smem + SX1 + 2625;           // 512
    float* agg  = smem + SX0;                  // 2048 (after build dead)
    int*   csrOffL = (int*)(smem + SCSRO);
    int*   csrColL = (int*)(smem + SCSRC);

    const float* xg; const int* eig; const float* eag;
    if (g < 128) {
        xg = x1 + (size_t)g * 4096; eig = ei1 + (size_t)g * 1024; eag = ea1 + (size_t)g * 512;
    } else {
        int h = g - 128;
        xg = x2 + (size_t)h * 4096; eig = ei2 + (size_t)h * 1024; eag = ea2 + (size_t)h * 512;
    }

    // ---- build: A image + dst-CSR edges + dedup CSR ----
    *(float4*)&xl[tid * 4] = *(const float4*)&xg[tid * 4];
    if (tid < 512) { srcl[tid] = eig[tid]; dstl[tid] = eig[512 + tid]; eal[tid] = eag[tid]; }
    for (int i = tid; i < 4224; i += UT) Al[i] = 0.f;
    chunkCnt[tid] = 0;
    __syncthreads();
    if (tid < 512) {
        Al[dstl[tid] * ASTR + srcl[tid]] = 1.f;
        atomicAdd(&chunkCnt[(tid >> 5) * 64 + dstl[tid]], 1);
    }
    __syncthreads();
    if (tid < 64) {
        Al[tid * ASTR + tid] = 0.f;
        int run = 0;
        for (int c = 0; c < 16; c++) {
            int t = chunkCnt[c * 64 + tid];
            chunkCnt[c * 64 + tid] = run; run += t;
        }
        sTot[tid] = run;
    }
    __syncthreads();
    if (tid < 64) {
        int v = sTot[tid]; int x = v;
        #pragma unroll
        for (int dl = 1; dl < 64; dl <<= 1) {
            int y = __shfl_up(x, dl);
            if (tid >= dl) x += y;
        }
        dOff[tid] = x - v;
        if (tid == 63) dOff[64] = x;
    }
    if (tid >= 64 && tid < 128) {
        int i = tid - 64; int c = 0;
        for (int j = 0; j < 64; j++) c += (Al[i * ASTR + j] != 0.f) ? 1 : 0;
        rowc[i] = c;
    }
    for (int i = tid; i < 2048; i += UT) rwl[i] = r1w[i];
    for (int i = tid; i < 4224; i += UT) wsA[(size_t)g * 4224 + i] = Al[i];
    __syncthreads();
    if (tid < 64) {
        int v = rowc[tid]; int x = v;
        #pragma unroll
        for (int dl = 1; dl < 64; dl <<= 1) {
            int y = __shfl_up(x, dl);
            if (tid >= dl) x += y;
        }
        csrOffL[tid] = x - v;
        if (tid == 63) csrOffL[64] = x;
    }
    __syncthreads();
    if (tid < 512) {
        int dk = dstl[tid]; int c = tid >> 5; int lr = 0;
        for (int e2 = (c << 5); e2 < tid; e2++) lr += (dstl[e2] == dk) ? 1 : 0;
        int pos = dOff[dk] + chunkCnt[c * 64 + dk] + lr;
        sSrc[pos] = srcl[tid]; sEa[pos] = eal[tid];
    }
    __syncthreads();
    if (tid < 64) {
        int p = csrOffL[tid];
        for (int j = 0; j < 64; j++)
            if (Al[tid * ASTR + j] != 0.f) {
                csrColL[p] = j;
                wsCsrC[(size_t)g * 512 + p] = j;
                p++;
            }
    }
    if (tid >= 64 && tid < 129) wsCsrO[(size_t)g * 66 + (tid - 64)] = csrOffL[tid - 64];
    if (tid >= 192 && tid < 257) wsEdg[(size_t)g * 1152 + (tid - 192)] = dOff[tid - 192];
    if (tid < 512) {
        wsEdg[(size_t)g * 1152 + 66 + tid] = sSrc[tid];
        ((float*)wsEdg)[(size_t)g * 1152 + 578 + tid] = sEa[tid];
    }
    __syncthreads();

    // ---- nnconv1: output straight into px (SX0, stride XS) ----
    nnconv_core<64>(xl, rwl, agg, dOff, sSrc, sEa, m1w, m1b, c1b,
                    smem + SX0, XS);

    // ---- unet1 (A + csr + px already resident) ----
    unet_body(smem, nullptr, nullptr, nullptr, nullptr,
              u0, u1, u2, u3, u4, u5, u6, u7, u8,
              ws_xs + (size_t)g * 9984, ws_As + (size_t)g * 6208,
              nullptr, g, -1);
    // final x in smem+SX1

    // ---- nnconv2 prep: xl2 <- relu(x), edges from ws, rwl2 ----
    float* xl2  = smem + SA;                  // 2048
    int*   dOff2 = (int*)(smem + SA + 2048);  // 65
    int*   sSrc2 = (int*)(smem + SA + 2113);  // 512
    float* sEa2  = smem + SA + 2625;          // 512
    float* rwl2  = smem + SB;                 // 1024
    float* agg2  = smem + SB + 1024;          // 2048
    {
        const float* xf = smem + SX1;
        for (int idx = tid; idx < 2048; idx += UT)
            xl2[idx] = fmaxf(xf[(idx >> 5) * XS + (idx & 31)], 0.f);
        if (tid < 1024) rwl2[tid] = r2w[tid];
        if (tid < 65) dOff2[tid] = wsEdg[(size_t)g * 1152 + tid];
        if (tid >= 128 && tid < 640) {
            sSrc2[tid - 128] = wsEdg[(size_t)g * 1152 + 66 + (tid - 128)];
            sEa2[tid - 128]  = ((const float*)wsEdg)[(size_t)g * 1152 + 578 + (tid - 128)];
        }
    }
    __syncthreads();
    nnconv_core<32>(xl2, rwl2, agg2, dOff2, sSrc2, sEa2, m2w, m2b, c2b,
                    xc2 + (size_t)g * 2048, 32);
}

// ---------------------------------------------------------------------------
// Kernel 2: unet2 + mean.
// ---------------------------------------------------------------------------
__global__ __launch_bounds__(UT, 4)
void unet2_kernel(const float* __restrict__ xc2, const float* __restrict__ wsA,
                  const int* __restrict__ wsCsrO, const int* __restrict__ wsCsrC,
                  const float* __restrict__ u0, const float* __restrict__ u1,
                  const float* __restrict__ u2, const float* __restrict__ u3,
                  const float* __restrict__ u4, const float* __restrict__ u5,
                  const float* __restrict__ u6, const float* __restrict__ u7,
                  const float* __restrict__ u8,
                  float* __restrict__ ws_xs, float* __restrict__ ws_As,
                  float* __restrict__ rr)
{
    const int g = blockIdx.x;
    __shared__ __align__(16) float smem[SMSZ];
    unet_body(smem, xc2 + (size_t)g * 2048, wsA + (size_t)g * 4224,
              wsCsrO + (size_t)g * 66, wsCsrC + (size_t)g * 512,
              u0, u1, u2, u3, u4, u5, u6, u7, u8,
              ws_xs + (size_t)g * 9984, ws_As + (size_t)g * 6208,
              rr, g, 1);
}

// ---------------------------------------------------------------------------
// Head: out[b,h] = relu([r1,jw1,r2,jw2] @ bb_w + bb_b)
// ---------------------------------------------------------------------------
__global__ __launch_bounds__(256)
void head_kernel(const float* __restrict__ r,
                 const float* __restrict__ jw1, const float* __restrict__ jw2,
                 const float* __restrict__ bw, const float* __restrict__ bb,
                 float* __restrict__ out)
{
    const int b = blockIdx.x, h = threadIdx.x;
    float acc = bb[h];
    const float* r1 = r + (size_t)b * 32;
    const float* r2 = r + (size_t)(128 + b) * 32;
    #pragma unroll
    for (int q = 0; q < 32; q++) acc += r1[q] * bw[q * 256 + h];
    #pragma unroll
    for (int q = 0; q < 16; q++) acc += jw1[b * 16 + q] * bw[(32 + q) * 256 + h];
    #pragma unroll
    for (int q = 0; q < 32; q++) acc += r2[q] * bw[(48 + q) * 256 + h];
    #pragma unroll
    for (int q = 0; q < 16; q++) acc += jw2[b * 16 + q] * bw[(80 + q) * 256 + h];
    out[(size_t)b * 256 + h] = fmaxf(acc, 0.f);
}

// ---------------------------------------------------------------------------
extern "C" void kernel_launch(void* const* d_in, const int* in_sizes, int n_in,
                              void* d_out, int out_size, void* d_ws, size_t ws_size,
                              hipStream_t stream)
{
    const float* x1  = (const float*)d_in[0];
    const int*   ei1 = (const int*)  d_in[1];
    const float* ea1 = (const float*)d_in[2];
    const float* jw1 = (const float*)d_in[3];
    const float* x2  = (const float*)d_in[4];
    const int*   ei2 = (const int*)  d_in[5];
    const float* ea2 = (const float*)d_in[6];
    const float* jw2 = (const float*)d_in[7];
    const float* m1w = (const float*)d_in[8];
    const float* m1b = (const float*)d_in[9];
    const float* r1w = (const float*)d_in[10];
    const float* c1b = (const float*)d_in[11];
    const float* m2w = (const float*)d_in[12];
    const float* m2b = (const float*)d_in[13];
    const float* r2w = (const float*)d_in[14];
    const float* c2b = (const float*)d_in[15];
    const float* u1p[9]; for (int i = 0; i < 9; i++) u1p[i] = (const float*)d_in[16 + i];
    const float* u2p[9]; for (int i = 0; i < 9; i++) u2p[i] = (const float*)d_in[25 + i];
    const float* bbw = (const float*)d_in[34];
    const float* bbb = (const float*)d_in[35];

    char* ws = (char*)d_ws;
    size_t off = 0;
    float* wsA  = (float*)(ws + off); off += 256ull * 4224 * 4;
    float* wxs  = (float*)(ws + off); off += 256ull * 9984 * 4;
    float* wAs  = (float*)(ws + off); off += 256ull * 6208 * 4;
    int*   wEdg = (int*)  (ws + off); off += 256ull * 1152 * 4;
    int*   wCsO = (int*)  (ws + off); off += 256ull * 66 * 4;
    int*   wCsC = (int*)  (ws + off); off += 256ull * 512 * 4;
    float* xc2  = (float*)(ws + off); off += 256ull * 2048 * 4;
    float* rr   = (float*)(ws + off); off += 256ull * 32 * 4;
    (void)ws_size; (void)in_sizes; (void)n_in; (void)out_size;

    fused1_kernel<<<256, UT, 0, stream>>>(
        x1, x2, ei1, ei2, ea1, ea2,
        m1w, m1b, r1w, c1b, m2w, m2b, r2w, c2b,
        u1p[0], u1p[1], u1p[2], u1p[3], u1p[4], u1p[5], u1p[6], u1p[7], u1p[8],
        wsA, wEdg, wCsO, wCsC, wxs, wAs, xc2);
    unet2_kernel<<<256, UT, 0, stream>>>(xc2, wsA, wCsO, wCsC,
        u2p[0], u2p[1], u2p[2], u2p[3], u2p[4], u2p[5], u2p[6], u2p[7], u2p[8],
        wxs, wAs, rr);
    head_kernel<<<128, 256, 0, stream>>>(rr, jw1, jw2, bbw, bbb, (float*)d_out);
}

// Round 11
// 309.440 us; speedup vs baseline: 1.2312x; 1.2312x over previous
//
#include <hip/hip_runtime.h>
#include <math.h>

#define UT 1024
#define XS 52      // x-buffer row stride (rows 16B-aligned)
#define ASTR 65    // A-buffer row stride (odd -> conflict-free column access)

__device__ __forceinline__ float wred16(float v) {
    v += __shfl_xor(v, 8); v += __shfl_xor(v, 4);
    v += __shfl_xor(v, 2); v += __shfl_xor(v, 1);
    return v;
}

// ---------------------------------------------------------------------------
// Dense GCN on LDS buffers. 2-row x 4-col register tiles; A rows read as
// adjacent b32 pairs (ds_read2_b32) so ASTR stays 65 (round-6 conflict
// profile). Accumulator pairing matches round 7 (bit-identical sums).
// ---------------------------------------------------------------------------
__device__ __forceinline__ void gcn_u(int n, int cin, int cout,
    float* __restrict__ x, float* __restrict__ tmp,
    const float* __restrict__ A, float* __restrict__ Wl,
    float* __restrict__ dis,
    const float* __restrict__ Wg, const float* __restrict__ bg, bool relu)
{
    const int tid = threadIdx.x;
    const int nso = (cout + 3) >> 2;
    for (int idx = tid; idx < 51 * 52; idx += UT) {
        int r = idx / 52, c = idx - r * 52;
        float v = 0.f;
        if (r < cin && c < cout) v = Wg[r * cout + c];
        else if (r == 50 && c < cout) v = bg[c];
        Wl[idx] = v;
    }
    {   // dis[i] = 1/sqrt(2 + rowsum(A))
        int r = tid >> 4, l = tid & 15;
        float s = 0.f;
        if (r < n) for (int j = l; j < n; j += 16) s += A[r * ASTR + j];
        s = wred16(s);
        if (l == 0 && r < n) dis[r] = 1.0f / sqrtf(2.0f + s);
    }
    __syncthreads();
    const int nr2 = n >> 1;
    const int items = nr2 * nso;
    // stage 1: tmp = dis * (x @ W), 2 rows per item (float2 x reads, XS even)
    for (int it = tid; it < items; it += UT) {
        int i0 = (it / nso) * 2, o0 = (it - (it / nso) * nso) * 4;
        float a0=0,a1=0,a2=0,a3=0, b0=0,b1=0,b2=0,b3=0;
        float c0=0,c1=0,c2=0,c3=0, d0=0,d1=0,d2=0,d3=0;
        for (int k = 0; k < cin; k += 2) {
            float4 w0 = *(const float4*)&Wl[k * 52 + o0];
            float4 w1 = *(const float4*)&Wl[(k + 1) * 52 + o0];
            float2 xa = *(const float2*)&x[i0 * XS + k];
            float2 xb = *(const float2*)&x[(i0 + 1) * XS + k];
            a0 = fmaf(xa.x, w0.x, a0); a1 = fmaf(xa.x, w0.y, a1);
            a2 = fmaf(xa.x, w0.z, a2); a3 = fmaf(xa.x, w0.w, a3);
            b0 = fmaf(xa.y, w1.x, b0); b1 = fmaf(xa.y, w1.y, b1);
            b2 = fmaf(xa.y, w1.z, b2); b3 = fmaf(xa.y, w1.w, b3);
            c0 = fmaf(xb.x, w0.x, c0); c1 = fmaf(xb.x, w0.y, c1);
            c2 = fmaf(xb.x, w0.z, c2); c3 = fmaf(xb.x, w0.w, c3);
            d0 = fmaf(xb.y, w1.x, d0); d1 = fmaf(xb.y, w1.y, d1);
            d2 = fmaf(xb.y, w1.z, d2); d3 = fmaf(xb.y, w1.w, d3);
        }
        float e0 = dis[i0], e1 = dis[i0 + 1];
        float4 t0, t1;
        t0.x = (a0 + b0) * e0; t0.y = (a1 + b1) * e0;
        t0.z = (a2 + b2) * e0; t0.w = (a3 + b3) * e0;
        t1.x = (c0 + d0) * e1; t1.y = (c1 + d1) * e1;
        t1.z = (c2 + d2) * e1; t1.w = (c3 + d3) * e1;
        *(float4*)&tmp[i0 * XS + o0] = t0;
        *(float4*)&tmp[(i0 + 1) * XS + o0] = t1;
    }
    __syncthreads();
    // stage 2: x = dis*(A@tmp + 2*tmp) + b, 2 rows per item (A as b32 pairs)
    for (int it = tid; it < items; it += UT) {
        int i0 = (it / nso) * 2, o0 = (it - (it / nso) * nso) * 4;
        float a0=0,a1=0,a2=0,a3=0, b0=0,b1=0,b2=0,b3=0;
        float c0=0,c1=0,c2=0,c3=0, d0=0,d1=0,d2=0,d3=0;
        for (int j = 0; j < n; j += 2) {
            float4 t0 = *(const float4*)&tmp[j * XS + o0];
            float4 t1 = *(const float4*)&tmp[(j + 1) * XS + o0];
            float Aax = A[i0 * ASTR + j],       Aay = A[i0 * ASTR + j + 1];
            float Abx = A[(i0 + 1) * ASTR + j], Aby = A[(i0 + 1) * ASTR + j + 1];
            a0 = fmaf(Aax, t0.x, a0); a1 = fmaf(Aax, t0.y, a1);
            a2 = fmaf(Aax, t0.z, a2); a3 = fmaf(Aax, t0.w, a3);
            b0 = fmaf(Aay, t1.x, b0); b1 = fmaf(Aay, t1.y, b1);
            b2 = fmaf(Aay, t1.z, b2); b3 = fmaf(Aay, t1.w, b3);
            c0 = fmaf(Abx, t0.x, c0); c1 = fmaf(Abx, t0.y, c1);
            c2 = fmaf(Abx, t0.z, c2); c3 = fmaf(Abx, t0.w, c3);
            d0 = fmaf(Aby, t1.x, d0); d1 = fmaf(Aby, t1.y, d1);
            d2 = fmaf(Aby, t1.z, d2); d3 = fmaf(Aby, t1.w, d3);
        }
        float4 bias = *(const float4*)&Wl[50 * 52 + o0];
        float4 s0 = *(const float4*)&tmp[i0 * XS + o0];
        float4 s1 = *(const float4*)&tmp[(i0 + 1) * XS + o0];
        float e0 = dis[i0], e1 = dis[i0 + 1];
        float4 r0, r1;
        r0.x = fmaf(e0, (a0 + b0) + 2.f * s0.x, bias.x);
        r0.y = fmaf(e0, (a1 + b1) + 2.f * s0.y, bias.y);
        r0.z = fmaf(e0, (a2 + b2) + 2.f * s0.z, bias.z);
        r0.w = fmaf(e0, (a3 + b3) + 2.f * s0.w, bias.w);
        r1.x = fmaf(e1, (c0 + d0) + 2.f * s1.x, bias.x);
        r1.y = fmaf(e1, (c1 + d1) + 2.f * s1.y, bias.y);
        r1.z = fmaf(e1, (c2 + d2) + 2.f * s1.z, bias.z);
        r1.w = fmaf(e1, (c3 + d3) + 2.f * s1.w, bias.w);
        if (relu) {
            r0.x = fmaxf(r0.x, 0.f); r0.y = fmaxf(r0.y, 0.f);
            r0.z = fmaxf(r0.z, 0.f); r0.w = fmaxf(r0.w, 0.f);
            r1.x = fmaxf(r1.x, 0.f); r1.y = fmaxf(r1.y, 0.f);
            r1.z = fmaxf(r1.z, 0.f); r1.w = fmaxf(r1.w, 0.f);
        }
        *(float4*)&x[i0 * XS + o0] = r0;
        *(float4*)&x[(i0 + 1) * XS + o0] = r1;
    }
    __syncthreads();
}

// ---------------------------------------------------------------------------
// Sparse GCN for n=64 with the ORIGINAL binary adjacency (dedup CSR).
// Stage-1 2-row tiles (float2 x); stage-2 1-row CSR (round-6, proven).
// ---------------------------------------------------------------------------
__device__ __forceinline__ void gcn_sparse(int cin, int cout,
    float* __restrict__ x, float* __restrict__ tmp,
    const int* __restrict__ csrOff, const int* __restrict__ csrCol,
    float* __restrict__ dis0, float* __restrict__ Wl,
    const float* __restrict__ Wg, const float* __restrict__ bg, bool relu)
{
    const int tid = threadIdx.x;
    const int nso = (cout + 3) >> 2;
    for (int idx = tid; idx < 51 * 52; idx += UT) {
        int r = idx / 52, c = idx - r * 52;
        float v = 0.f;
        if (r < cin && c < cout) v = Wg[r * cout + c];
        else if (r == 50 && c < cout) v = bg[c];
        Wl[idx] = v;
    }
    if (tid < 64)
        dis0[tid] = 1.0f / sqrtf(2.0f + (float)(csrOff[tid + 1] - csrOff[tid]));
    __syncthreads();
    const int items1 = 32 * nso;
    if (tid < items1) {
        int i0 = (tid / nso) * 2, o0 = (tid - (tid / nso) * nso) * 4;
        float a0=0,a1=0,a2=0,a3=0, b0=0,b1=0,b2=0,b3=0;
        float c0=0,c1=0,c2=0,c3=0, d0=0,d1=0,d2=0,d3=0;
        for (int k = 0; k < cin; k += 2) {
            float4 w0 = *(const float4*)&Wl[k * 52 + o0];
            float4 w1 = *(const float4*)&Wl[(k + 1) * 52 + o0];
            float2 xa = *(const float2*)&x[i0 * XS + k];
            float2 xb = *(const float2*)&x[(i0 + 1) * XS + k];
            a0 = fmaf(xa.x, w0.x, a0); a1 = fmaf(xa.x, w0.y, a1);
            a2 = fmaf(xa.x, w0.z, a2); a3 = fmaf(xa.x, w0.w, a3);
            b0 = fmaf(xa.y, w1.x, b0); b1 = fmaf(xa.y, w1.y, b1);
            b2 = fmaf(xa.y, w1.z, b2); b3 = fmaf(xa.y, w1.w, b3);
            c0 = fmaf(xb.x, w0.x, c0); c1 = fmaf(xb.x, w0.y, c1);
            c2 = fmaf(xb.x, w0.z, c2); c3 = fmaf(xb.x, w0.w, c3);
            d0 = fmaf(xb.y, w1.x, d0); d1 = fmaf(xb.y, w1.y, d1);
            d2 = fmaf(xb.y, w1.z, d2); d3 = fmaf(xb.y, w1.w, d3);
        }
        float e0 = dis0[i0], e1 = dis0[i0 + 1];
        float4 t0, t1;
        t0.x = (a0 + b0) * e0; t0.y = (a1 + b1) * e0;
        t0.z = (a2 + b2) * e0; t0.w = (a3 + b3) * e0;
        t1.x = (c0 + d0) * e1; t1.y = (c1 + d1) * e1;
        t1.z = (c2 + d2) * e1; t1.w = (c3 + d3) * e1;
        *(float4*)&tmp[i0 * XS + o0] = t0;
        *(float4*)&tmp[(i0 + 1) * XS + o0] = t1;
    }
    __syncthreads();
    const int items = 64 * nso;
    if (tid < items) {
        int i = tid / nso, o0 = (tid - i * nso) * 4;
        int base = csrOff[i], end = csrOff[i + 1];
        float a0 = 0.f, a1 = 0.f, a2 = 0.f, a3 = 0.f;
        for (int p = base; p < end; p++) {
            int j = csrCol[p];
            float4 t = *(const float4*)&tmp[j * XS + o0];
            a0 += t.x; a1 += t.y; a2 += t.z; a3 += t.w;
        }
        float4 bias = *(const float4*)&Wl[50 * 52 + o0];
        float4 s0 = *(const float4*)&tmp[i * XS + o0];
        float d = dis0[i];
        float4 r;
        r.x = fmaf(d, a0 + 2.f * s0.x, bias.x);
        r.y = fmaf(d, a1 + 2.f * s0.y, bias.y);
        r.z = fmaf(d, a2 + 2.f * s0.z, bias.z);
        r.w = fmaf(d, a3 + 2.f * s0.w, bias.w);
        if (relu) {
            r.x = fmaxf(r.x, 0.f); r.y = fmaxf(r.y, 0.f);
            r.z = fmaxf(r.z, 0.f); r.w = fmaxf(r.w, 0.f);
        }
        *(float4*)&x[i * XS + o0] = r;
    }
    __syncthreads();
}

// ---------------------------------------------------------------------------
__device__ __forceinline__ void down_scores(int n, const float* __restrict__ wg,
                                            const float* __restrict__ px,
                                            float* __restrict__ scr)
{
    const int tid = threadIdx.x;
    int r = tid >> 4, l = tid & 15;
    float s = 0.f, wn = 0.f;
    for (int q = l; q < 50; q += 16) {
        float wv = wg[q];
        wn = fmaf(wv, wv, wn);
        s  = fmaf(px[r * XS + q], wv, s);
    }
    s = wred16(s); wn = wred16(wn);
    if (l == 0 && r < n) scr[r] = tanhf(s / sqrtf(wn));
}

__device__ __forceinline__ void down_rest(int n, int kk,
    float* __restrict__ px, float* __restrict__ pt_,
    float* __restrict__ pA, float* __restrict__ pF,
    float* __restrict__ scr, float* __restrict__ dis, float* __restrict__ svals,
    int* __restrict__ perm, const float* __restrict__ dw,
    const float* __restrict__ db)
{
    const int tid = threadIdx.x;
    __syncthreads();
    // bitonic top-k on wave 0 (desc score, asc index — lax.top_k semantics)
    if (tid < 64) {
        float v = (tid < n) ? scr[tid] : -2.0f;
        int id = tid;
        for (int sz = 2; sz <= 64; sz <<= 1)
            for (int st = sz >> 1; st > 0; st >>= 1) {
                float ov = __shfl_xor(v, st);
                int oi = __shfl_xor(id, st);
                bool up = ((tid & sz) == 0);
                bool lower = ((tid & st) == 0);
                bool less = (v > ov) || (v == ov && id < oi);
                bool keep = (up == lower) ? less : !less;
                if (!keep) { v = ov; id = oi; }
            }
        if (tid < kk) { perm[tid] = id; svals[tid] = v; }
    }
    __syncthreads();
    // Ag = Aold[:, perm] into pt_ (zero-padded cols); gather x -> regs
    for (int idx = tid; idx < n * 13; idx += UT) {
        int m = idx / 13, u0 = (idx - (idx / 13) * 13) * 4;
        float4 gv;
        gv.x = (u0 + 0 < kk) ? pA[m * ASTR + perm[u0 + 0]] : 0.f;
        gv.y = (u0 + 1 < kk) ? pA[m * ASTR + perm[u0 + 1]] : 0.f;
        gv.z = (u0 + 2 < kk) ? pA[m * ASTR + perm[u0 + 2]] : 0.f;
        gv.w = (u0 + 3 < kk) ? pA[m * ASTR + perm[u0 + 3]] : 0.f;
        *(float4*)&pt_[m * XS + u0] = gv;
    }
    float gx0=0, gx1=0, gx2=0, gx3=0; int gdst = -1;
    if (tid < kk * 13) {
        int t = tid / 13, q0 = (tid - t * 13) * 4;
        float sv = svals[t]; int p = perm[t];
        gx0 = px[p * XS + q0 + 0] * sv; gx1 = px[p * XS + q0 + 1] * sv;
        gx2 = px[p * XS + q0 + 2] * sv; gx3 = px[p * XS + q0 + 3] * sv;
        gdst = t * XS + q0;
    }
    __syncthreads();
    if (gdst >= 0) {
        px[gdst] = gx0; px[gdst + 1] = gx1; px[gdst + 2] = gx2; px[gdst + 3] = gx3;
    }
    // Anew[t,u] = 2*Ag[pt,u] + sum_m Aold[pt,m]*Ag[m,u]  (2-row x 4-col items)
    int nst = (kk + 3) >> 2, kt2 = kk >> 1;
    for (int it = tid; it < kt2 * nst; it += UT) {
        int t0 = (it / nst) * 2, u0 = (it - (it / nst) * nst) * 4;
        int p0 = perm[t0], p1 = perm[t0 + 1];
        float a0=0,a1=0,a2=0,a3=0, b0=0,b1=0,b2=0,b3=0;
        float c0=0,c1=0,c2=0,c3=0, d0=0,d1=0,d2=0,d3=0;
        for (int m = 0; m < n; m += 2) {
            float4 g0 = *(const float4*)&pt_[m * XS + u0];
            float4 g1 = *(const float4*)&pt_[(m + 1) * XS + u0];
            float q0x = pA[p0 * ASTR + m], q0y = pA[p0 * ASTR + m + 1];
            float q1x = pA[p1 * ASTR + m], q1y = pA[p1 * ASTR + m + 1];
            a0 = fmaf(q0x, g0.x, a0); a1 = fmaf(q0x, g0.y, a1);
            a2 = fmaf(q0x, g0.z, a2); a3 = fmaf(q0x, g0.w, a3);
            b0 = fmaf(q0y, g1.x, b0); b1 = fmaf(q0y, g1.y, b1);
            b2 = fmaf(q0y, g1.z, b2); b3 = fmaf(q0y, g1.w, b3);
            c0 = fmaf(q1x, g0.x, c0); c1 = fmaf(q1x, g0.y, c1);
            c2 = fmaf(q1x, g0.z, c2); c3 = fmaf(q1x, g0.w, c3);
            d0 = fmaf(q1y, g1.x, d0); d1 = fmaf(q1y, g1.y, d1);
            d2 = fmaf(q1y, g1.z, d2); d3 = fmaf(q1y, g1.w, d3);
        }
        float4 gg0 = *(const float4*)&pt_[p0 * XS + u0];
        float4 gg1 = *(const float4*)&pt_[p1 * XS + u0];
        float v;
        v = (a0 + b0) + 2.f * gg0.x; pF[t0 * ASTR + u0 + 0] = (u0 + 0 == t0) ? 0.f : v;
        v = (a1 + b1) + 2.f * gg0.y; pF[t0 * ASTR + u0 + 1] = (u0 + 1 == t0) ? 0.f : v;
        v = (a2 + b2) + 2.f * gg0.z; pF[t0 * ASTR + u0 + 2] = (u0 + 2 == t0) ? 0.f : v;
        v = (a3 + b3) + 2.f * gg0.w; pF[t0 * ASTR + u0 + 3] = (u0 + 3 == t0) ? 0.f : v;
        v = (c0 + d0) + 2.f * gg1.x; pF[(t0+1) * ASTR + u0 + 0] = (u0 + 0 == t0+1) ? 0.f : v;
        v = (c1 + d1) + 2.f * gg1.y; pF[(t0+1) * ASTR + u0 + 1] = (u0 + 1 == t0+1) ? 0.f : v;
        v = (c2 + d2) + 2.f * gg1.z; pF[(t0+1) * ASTR + u0 + 2] = (u0 + 2 == t0+1) ? 0.f : v;
        v = (c3 + d3) + 2.f * gg1.w; pF[(t0+1) * ASTR + u0 + 3] = (u0 + 3 == t0+1) ? 0.f : v;
    }
    __syncthreads();
    gcn_u(kk, 50, 50, px, pt_, pF, pA, dis, dw, db, true);
}

// ---------------------------------------------------------------------------
// UNet kernel (round-6 structure, ASTR=65): one block per graph.
// ---------------------------------------------------------------------------
__global__ __launch_bounds__(UT)
void unet_kernel(const float* __restrict__ xin, const float* __restrict__ wsA,
                 const int* __restrict__ wsCsrO, const int* __restrict__ wsCsrC,
                 const float* __restrict__ dw0, const float* __restrict__ db0,
                 const float* __restrict__ dws, const float* __restrict__ dbs,
                 const float* __restrict__ pws,
                 const float* __restrict__ uws, const float* __restrict__ ubs,
                 const float* __restrict__ uwl, const float* __restrict__ ubl,
                 float* __restrict__ ws_xs, float* __restrict__ ws_As,
                 float* __restrict__ outp, int mean_mode)
{
    const int g = blockIdx.x, tid = threadIdx.x;
    __shared__ __align__(16) float Aa[64 * ASTR];
    __shared__ __align__(16) float Ab[64 * ASTR];
    __shared__ __align__(16) float x0c[64 * XS];
    __shared__ __align__(16) float x1c[64 * XS];
    __shared__ float scr[64];
    __shared__ float dis[64];
    __shared__ float dis0[64];
    __shared__ float svals[64];
    __shared__ int   permL[192];
    __shared__ int   csrOffL[65];
    __shared__ int   csrColL[512];

    float *pA = Aa, *pF = Ab, *px = x0c, *pt_ = x1c;
    float* xs_g = ws_xs + (size_t)g * 9984;   // 3 x 3328
    float* as_g = ws_As + (size_t)g * 6144;   // A1(3380) + A2(2730)
    const float* wsAg = wsA + (size_t)g * 4160;
    const int nsz[4] = {64, 52, 42, 34};

    {   // initial loads
        const float* xg = xin + (size_t)g * 2048;
        for (int idx = tid; idx < 512; idx += UT) {
            int i = idx >> 3, o0 = (idx & 7) * 4;
            *(float4*)&px[i * XS + o0] = *(const float4*)&xg[i * 32 + o0];
        }
        for (int idx = tid; idx < 4160; idx += UT) pA[idx] = wsAg[idx];
        if (tid < 65) csrOffL[tid] = wsCsrO[(size_t)g * 66 + tid];
        if (tid >= 128 && tid < 640) csrColL[tid - 128] = wsCsrC[(size_t)g * 512 + tid - 128];
    }
    __syncthreads();

    gcn_sparse(32, 50, px, pt_, csrOffL, csrColL, dis0, pF, dw0, db0, true);

    // ---- down path ----
    for (int lvl = 0; lvl < 3; lvl++) {
        int n = nsz[lvl], kk = nsz[lvl + 1];
        down_scores(n, pws + lvl * 50, px, scr);
        {   // skip saves
            float* xd = xs_g + lvl * 3328;
            for (int idx = tid; idx < 3328; idx += UT) xd[idx] = px[idx];
            if (lvl == 1) for (int idx = tid; idx < 3380; idx += UT) as_g[idx] = pA[idx];
            if (lvl == 2) for (int idx = tid; idx < 2730; idx += UT) as_g[3380 + idx] = pA[idx];
        }
        down_rest(n, kk, px, pt_, pA, pF, scr, dis, svals, permL + lvl * 64,
                  dws + lvl * 2500, dbs + lvl * 50);
        { float* t = pA; pA = pF; pF = t; }
    }

    // ---- up path ----
    for (int i2 = 0; i2 < 3; i2++) {
        int j = 2 - i2;
        int kc = nsz[j + 1];
        {   // residual into pt_; A into pF for dense levels only
            const float* resg = xs_g + j * 3328;
            for (int idx = tid; idx < 3328; idx += UT) pt_[idx] = resg[idx];
            if (j == 1) {
                for (int idx = tid; idx < 3380; idx += UT) pF[idx] = as_g[idx];
            } else if (j == 2) {
                for (int idx = tid; idx < 2730; idx += UT) pF[idx] = as_g[3380 + idx];
            }
        }
        __syncthreads();
        const int* perm = permL + j * 64;
        for (int it = tid; it < kc * 13; it += UT) {
            int t = it / 13, q0 = (it - t * 13) * 4;
            int p = perm[t];
            pt_[p*XS+q0+0] += px[t*XS+q0+0]; pt_[p*XS+q0+1] += px[t*XS+q0+1];
            pt_[p*XS+q0+2] += px[t*XS+q0+2]; pt_[p*XS+q0+3] += px[t*XS+q0+3];
        }
        __syncthreads();
        if (i2 < 2)
            gcn_u(nsz[j], 50, 50, pt_, px, pF, pA, dis, uws + i2 * 2500, ubs + i2 * 50, true);
        else
            gcn_sparse(50, 32, pt_, px, csrOffL, csrColL, dis0, pF, uwl, ubl, false);
        { float* t2 = px; px = pt_; pt_ = t2; }
        { float* t2 = pA; pA = pF; pF = t2; }
    }

    // epilogue
    if (mean_mode) {
        int r = tid >> 4, l = tid & 15;
        if (r < 32) {
            float s = 0.f;
            for (int i = l; i < 64; i += 16) s += fmaxf(px[i * XS + r], 0.f);
            s = wred16(s);
            if (l == 0) outp[(size_t)g * 32 + r] = s * (1.0f / 64.0f);
        }
    } else {
        float* og = outp + (size_t)g * 2048;
        for (int idx = tid; idx < 512; idx += UT) {
            int i = idx >> 3, o0 = (idx & 7) * 4;
            float4 vv = *(const float4*)&px[i * XS + o0];
            vv.x = fmaxf(vv.x, 0.f); vv.y = fmaxf(vv.y, 0.f);
            vv.z = fmaxf(vv.z, 0.f); vv.w = fmaxf(vv.w, 0.f);
            *(float4*)&og[i * 32 + o0] = vv;
        }
    }
}

// ---------------------------------------------------------------------------
// NNConv core, dst-grouped & atomic-free (round-6, proven).
// ---------------------------------------------------------------------------
template<int FIN>
__device__ __forceinline__ void nnconv_core(
    const float* __restrict__ xl, const float* __restrict__ rwl,
    float* __restrict__ agg,
    const int* __restrict__ dOff, const int* __restrict__ sSrc,
    const float* __restrict__ sEa,
    const float* __restrict__ mw, const float* __restrict__ mb,
    const float* __restrict__ bias, float* __restrict__ xout_g)
{
    constexpr int CH = FIN / 2;
    const int tid = threadIdx.x;
    const int o = tid & 31, ic = (tid >> 5) & 1, wv = tid >> 6;
    float mwr[CH], mbr[CH];
    #pragma unroll
    for (int z = 0; z < CH; z++) {
        mwr[z] = mw[(ic * CH + z) * 32 + o];
        mbr[z] = mb[(ic * CH + z) * 32 + o];
    }
    for (int dd = 0; dd < 4; dd++) {
        int d = wv * 4 + dd;                  // wave-uniform
        int b = dOff[d], e = dOff[d + 1];
        float ac0 = 0.f, ac1 = 0.f, ac2 = 0.f, ac3 = 0.f;
        for (int p = b; p < e; p++) {
            int s = sSrc[p];                  // broadcast
            float av = sEa[p];
            #pragma unroll
            for (int z = 0; z < CH; z += 4) {
                float4 xv = *(const float4*)&xl[s * FIN + ic * CH + z];
                ac0 = fmaf(xv.x, fmaxf(fmaf(av, mwr[z + 0], mbr[z + 0]), 0.f), ac0);
                ac1 = fmaf(xv.y, fmaxf(fmaf(av, mwr[z + 1], mbr[z + 1]), 0.f), ac1);
                ac2 = fmaf(xv.z, fmaxf(fmaf(av, mwr[z + 2], mbr[z + 2]), 0.f), ac2);
                ac3 = fmaf(xv.w, fmaxf(fmaf(av, mwr[z + 3], mbr[z + 3]), 0.f), ac3);
            }
        }
        float acc = (ac0 + ac1) + (ac2 + ac3);
        acc += __shfl_down(acc, 32);          // fold ic=1 into ic=0
        if (ic == 0) agg[d * 32 + o] = acc;   // unique writer, no atomic
    }
    __syncthreads();
    {   // epilogue: 1024 items = (node, o-pair)
        int nn = tid >> 4, o0 = (tid & 15) * 2;
        float a0 = 0.f, a1 = 0.f, b0 = 0.f, b1 = 0.f;
        for (int i = 0; i < FIN; i += 2) {
            float xv0 = xl[nn * FIN + i], xv1 = xl[nn * FIN + i + 1];
            float2 w0 = *(const float2*)&rwl[i * 32 + o0];
            float2 w1 = *(const float2*)&rwl[(i + 1) * 32 + o0];
            a0 = fmaf(xv0, w0.x, a0); a1 = fmaf(xv0, w0.y, a1);
            b0 = fmaf(xv1, w1.x, b0); b1 = fmaf(xv1, w1.y, b1);
        }
        float cn  = (float)(dOff[nn + 1] - dOff[nn]);
        float inv = 1.0f / fmaxf(cn, 1.f);
        float2 sv = *(const float2*)&agg[nn * 32 + o0];
        xout_g[nn * 32 + o0]     = fmaxf(fmaf(sv.x, inv, (a0 + b0) + bias[o0]),     0.f);
        xout_g[nn * 32 + o0 + 1] = fmaxf(fmaf(sv.y, inv, (a1 + b1) + bias[o0 + 1]), 0.f);
    }
}

// ---------------------------------------------------------------------------
// NNConv1 (FIN=64): builds A image (stride 65) + dedup CSR + stable
// dst-sorted edge list (persisted to ws), then runs the atomic-free conv.
// (byte-identical to round-6 champion)
// ---------------------------------------------------------------------------
__global__ __launch_bounds__(UT)
void nnconv1_kernel(const float* __restrict__ x1, const float* __restrict__ x2,
                    const int* __restrict__ ei1, const int* __restrict__ ei2,
                    const float* __restrict__ ea1, const float* __restrict__ ea2,
                    const float* __restrict__ mw, const float* __restrict__ mb,
                    const float* __restrict__ rw, const float* __restrict__ bias,
                    float* __restrict__ wsA, int* __restrict__ wsEdg,
                    int* __restrict__ wsCsrO, int* __restrict__ wsCsrC,
                    float* __restrict__ xout)
{
    const int g = blockIdx.x, tid = threadIdx.x;
    __shared__ __align__(16) float xl[4096];
    __shared__ __align__(16) float rwl[2048];
    __shared__ __align__(16) float agg[2048];    // aliased as chunkCnt in build
    __shared__ __align__(16) float Al[4160];
    __shared__ int   srcl[512];
    __shared__ int   dstl[512];
    __shared__ float eal[512];
    __shared__ int   sSrc[512];
    __shared__ float sEaL[512];
    __shared__ int   sTot[64];
    __shared__ int   dOff[65];
    __shared__ int   rowc[64];
    __shared__ int   csrOffL[65];

    const float* xg; const int* eig; const float* eag;
    if (g < 128) {
        xg = x1 + (size_t)g * 4096; eig = ei1 + (size_t)g * 1024; eag = ea1 + (size_t)g * 512;
    } else {
        int h = g - 128;
        xg = x2 + (size_t)h * 4096; eig = ei2 + (size_t)h * 1024; eag = ea2 + (size_t)h * 512;
    }
    int* chunkCnt = (int*)agg;                   // 16 chunks x 64 dsts

    // step 1: loads + zeroing
    *(float4*)&xl[tid * 4] = *(const float4*)&xg[tid * 4];   // 1024 x float4
    if (tid < 512) { srcl[tid] = eig[tid]; dstl[tid] = eig[512 + tid]; eal[tid] = eag[tid]; }
    for (int i = tid; i < 4160; i += UT) Al[i] = 0.f;
    chunkCnt[tid] = 0;
    __syncthreads();
    // step 2: A scatter + per-chunk dst counts
    if (tid < 512) {
        Al[dstl[tid] * ASTR + srcl[tid]] = 1.f;
        atomicAdd(&chunkCnt[(tid >> 5) * 64 + dstl[tid]], 1);
    }
    __syncthreads();
    // step 3: diag zero; per-dst chunk-exclusive run
    if (tid < 64) {
        Al[tid * ASTR + tid] = 0.f;
        int run = 0;
        for (int c = 0; c < 16; c++) {
            int t = chunkCnt[c * 64 + tid];
            chunkCnt[c * 64 + tid] = run; run += t;
        }
        sTot[tid] = run;
    }
    __syncthreads();
    // step 4: dst prefix (wave 0); csr row counts; rwl; persist wsA
    if (tid < 64) {
        int v = sTot[tid]; int x = v;
        #pragma unroll
        for (int dl = 1; dl < 64; dl <<= 1) {
            int y = __shfl_up(x, dl);
            if (tid >= dl) x += y;
        }
        dOff[tid] = x - v;
        if (tid == 63) dOff[64] = x;
    }
    if (tid >= 64 && tid < 128) {
        int i = tid - 64; int c = 0;
        for (int j = 0; j < 64; j++) c += (Al[i * ASTR + j] != 0.f) ? 1 : 0;
        rowc[i] = c;
    }
    for (int i = tid; i < 2048; i += UT) rwl[i] = rw[i];
    for (int i = tid; i < 4160; i += UT) wsA[(size_t)g * 4160 + i] = Al[i];
    __syncthreads();
    // step 5: csr prefix (wave 0); stable dst-sorted scatter
    if (tid < 64) {
        int v = rowc[tid]; int x = v;
        #pragma unroll
        for (int dl = 1; dl < 64; dl <<= 1) {
            int y = __shfl_up(x, dl);
            if (tid >= dl) x += y;
        }
        csrOffL[tid] = x - v;
        if (tid == 63) csrOffL[64] = x;
    }
    if (tid < 512) {
        int dk = dstl[tid]; int c = tid >> 5; int lr = 0;
        for (int e2 = (c << 5); e2 < tid; e2++) lr += (dstl[e2] == dk) ? 1 : 0;
        int pos = dOff[dk] + chunkCnt[c * 64 + dk] + lr;
        sSrc[pos] = srcl[tid]; sEaL[pos] = eal[tid];
    }
    __syncthreads();
    // step 6: persist csr + dst-sorted edges + dOff
    if (tid < 64) {
        int p = csrOffL[tid];
        for (int j = 0; j < 64; j++)
            if (Al[tid * ASTR + j] != 0.f) wsCsrC[(size_t)g * 512 + (p++)] = j;
    }
    if (tid >= 64 && tid < 129) wsCsrO[(size_t)g * 66 + (tid - 64)] = csrOffL[tid - 64];
    if (tid >= 192 && tid < 257) wsEdg[(size_t)g * 1152 + (tid - 192)] = dOff[tid - 192];
    if (tid < 512) {
        wsEdg[(size_t)g * 1152 + 66 + tid] = sSrc[tid];
        ((float*)wsEdg)[(size_t)g * 1152 + 578 + tid] = sEaL[tid];
    }
    __syncthreads();

    nnconv_core<64>(xl, rwl, agg, dOff, sSrc, sEaL, mw, mb, bias,
                    xout + (size_t)g * 2048);
}

// ---------------------------------------------------------------------------
// NNConv2 (FIN=32): loads pre-built dst-CSR edges from ws.
// ---------------------------------------------------------------------------
__global__ __launch_bounds__(UT)
void nnconv2_kernel(const float* __restrict__ xin,
                    const int* __restrict__ wsEdg,
                    const float* __restrict__ mw, const float* __restrict__ mb,
                    const float* __restrict__ rw, const float* __restrict__ bias,
                    float* __restrict__ xout)
{
    const int g = blockIdx.x, tid = threadIdx.x;
    __shared__ __align__(16) float xl[2048];
    __shared__ __align__(16) float rwl[1024];
    __shared__ __align__(16) float agg[2048];
    __shared__ int   dOff[65];
    __shared__ int   sSrc[512];
    __shared__ float sEaL[512];

    const float* xg = xin + (size_t)g * 2048;
    if (tid < 512) *(float4*)&xl[tid * 4] = *(const float4*)&xg[tid * 4];
    if (tid < 1024) rwl[tid] = rw[tid];
    if (tid < 65) dOff[tid] = wsEdg[(size_t)g * 1152 + tid];
    if (tid >= 128 && tid < 640) {
        sSrc[tid - 128] = wsEdg[(size_t)g * 1152 + 66 + (tid - 128)];
        sEaL[tid - 128] = ((const float*)wsEdg)[(size_t)g * 1152 + 578 + (tid - 128)];
    }
    __syncthreads();

    nnconv_core<32>(xl, rwl, agg, dOff, sSrc, sEaL, mw, mb, bias,
                    xout + (size_t)g * 2048);
}

// ---------------------------------------------------------------------------
// Head: out[b,h] = relu([r1,jw1,r2,jw2] @ bb_w + bb_b)
// ---------------------------------------------------------------------------
__global__ __launch_bounds__(256)
void head_kernel(const float* __restrict__ r,
                 const float* __restrict__ jw1, const float* __restrict__ jw2,
                 const float* __restrict__ bw, const float* __restrict__ bb,
                 float* __restrict__ out)
{
    const int b = blockIdx.x, h = threadIdx.x;
    float acc = bb[h];
    const float* r1 = r + (size_t)b * 32;
    const float* r2 = r + (size_t)(128 + b) * 32;
    #pragma unroll
    for (int q = 0; q < 32; q++) acc += r1[q] * bw[q * 256 + h];
    #pragma unroll
    for (int q = 0; q < 16; q++) acc += jw1[b * 16 + q] * bw[(32 + q) * 256 + h];
    #pragma unroll
    for (int q = 0; q < 32; q++) acc += r2[q] * bw[(48 + q) * 256 + h];
    #pragma unroll
    for (int q = 0; q < 16; q++) acc += jw2[b * 16 + q] * bw[(80 + q) * 256 + h];
    out[(size_t)b * 256 + h] = fmaxf(acc, 0.f);
}

// ---------------------------------------------------------------------------
extern "C" void kernel_launch(void* const* d_in, const int* in_sizes, int n_in,
                              void* d_out, int out_size, void* d_ws, size_t ws_size,
                              hipStream_t stream)
{
    const float* x1  = (const float*)d_in[0];
    const int*   ei1 = (const int*)  d_in[1];
    const float* ea1 = (const float*)d_in[2];
    const float* jw1 = (const float*)d_in[3];
    const float* x2  = (const float*)d_in[4];
    const int*   ei2 = (const int*)  d_in[5];
    const float* ea2 = (const float*)d_in[6];
    const float* jw2 = (const float*)d_in[7];
    const float* m1w = (const float*)d_in[8];
    const float* m1b = (const float*)d_in[9];
    const float* r1w = (const float*)d_in[10];
    const float* c1b = (const float*)d_in[11];
    const float* m2w = (const float*)d_in[12];
    const float* m2b = (const float*)d_in[13];
    const float* r2w = (const float*)d_in[14];
    const float* c2b = (const float*)d_in[15];
    const float* u1p[9]; for (int i = 0; i < 9; i++) u1p[i] = (const float*)d_in[16 + i];
    const float* u2p[9]; for (int i = 0; i < 9; i++) u2p[i] = (const float*)d_in[25 + i];
    const float* bbw = (const float*)d_in[34];
    const float* bbb = (const float*)d_in[35];

    char* ws = (char*)d_ws;
    size_t off = 0;
    float* wsA  = (float*)(ws + off); off += 256ull * 4160 * 4;
    float* xc1  = (float*)(ws + off); off += 256ull * 2048 * 4;
    float* xu1  = (float*)(ws + off); off += 256ull * 2048 * 4;
    float* xc2  = (float*)(ws + off); off += 256ull * 2048 * 4;
    float* rr   = (float*)(ws + off); off += 256ull * 32 * 4;
    float* wxs  = (float*)(ws + off); off += 256ull * 9984 * 4;
    float* wAs  = (float*)(ws + off); off += 256ull * 6144 * 4;
    int*   wEdg = (int*)  (ws + off); off += 256ull * 1152 * 4;
    int*   wCsO = (int*)  (ws + off); off += 256ull * 66 * 4;
    int*   wCsC = (int*)  (ws + off); off += 256ull * 512 * 4;
    (void)ws_size; (void)in_sizes; (void)n_in; (void)out_size;

    nnconv1_kernel<<<256, UT, 0, stream>>>(x1, x2, ei1, ei2, ea1, ea2,
                                           m1w, m1b, r1w, c1b,
                                           wsA, wEdg, wCsO, wCsC, xc1);
    unet_kernel<<<256, UT, 0, stream>>>(xc1, wsA, wCsO, wCsC,
        u1p[0], u1p[1], u1p[2], u1p[3], u1p[4], u1p[5], u1p[6], u1p[7], u1p[8],
        wxs, wAs, xu1, 0);
    nnconv2_kernel<<<256, UT, 0, stream>>>(xu1, wEdg, m2w, m2b, r2w, c2b, xc2);
    unet_kernel<<<256, UT, 0, stream>>>(xc2, wsA, wCsO, wCsC,
        u2p[0], u2p[1], u2p[2], u2p[3], u2p[4], u2p[5], u2p[6], u2p[7], u2p[8],
        wxs, wAs, rr, 1);
    head_kernel<<<128, 256, 0, stream>>>(rr, jw1, jw2, bbw, bbb, (float*)d_out);
}